// Round 15
// baseline (105.797 us; speedup 1.0000x reference)
//
#include <hip/hip_runtime.h>

// Single-head causal attention. Round 15: PB=4 batches per 1024-thread block
// (16 waves/CU in one domain — same wave count as the 103µs R14, but wt DMA
// halved to 147 MB). x tri-buffered LDS staging + wt dbuf, derived per-wave
// counted vmcnt; all layouts identical to verified R14.
// B=2048, T=64, C=768, H=64. Inputs fp32: x, Wk, Wq, Wv ([in,out] layout).

#define BATCHES 2048
#define SEQ 64
#define CDIM 768
#define HDIM 64
#define NCHUNK 24  // 768 / 32
#define PB 4

typedef __bf16 bf16x8 __attribute__((ext_vector_type(8)));
typedef float f32x4v __attribute__((ext_vector_type(4)));
typedef unsigned short u16x8 __attribute__((ext_vector_type(8)));

__device__ __forceinline__ unsigned short f2bf(float f) {
  return __builtin_bit_cast(unsigned short, (__bf16)f);
}

// XOR swizzle for 64-elem bf16 parking rows: elem col ^= ((row&7)<<3)
__device__ __forceinline__ int swz(int row, int col) {
  return row * 64 + (col ^ ((row & 7) << 3));
}

__device__ __forceinline__ f32x4v mfma16(bf16x8 a, bf16x8 b, f32x4v c) {
  return __builtin_amdgcn_mfma_f32_16x16x32_bf16(a, b, c, 0, 0, 0);
}

__device__ __forceinline__ bf16x8 lds_frag(const unsigned short* p, int row, int col) {
  return __builtin_bit_cast(bf16x8, *reinterpret_cast<const u16x8*>(p + swz(row, col)));
}

__device__ __forceinline__ void gl_lds16(const void* g, void* l) {
  __builtin_amdgcn_global_load_lds(
      (const __attribute__((address_space(1))) void*)g,
      (__attribute__((address_space(3))) void*)l, 16, 0, 0);
}

// Prep (verified R4/R7/R10/R14): chunk-major, chunk stride 12288 B (unpadded).
// ws element i: c = i/6144, slot = (i%6144)>>3, e = i&7;
// row = slot>>2 (mat*64+h), p = slot&3, g = p^((row>>1)&3), k = c*32+g*8+e.
__global__ __launch_bounds__(256) void prep_wt_kernel(
    const float* __restrict__ Wk, const float* __restrict__ Wq,
    const float* __restrict__ Wv, unsigned short* __restrict__ wt) {
  int i = blockIdx.x * 256 + threadIdx.x;
  if (i >= 3 * HDIM * CDIM) return;
  int c = i / 6144;
  int r2 = i - c * 6144;
  int slot = r2 >> 3;
  int e = r2 & 7;
  int row = slot >> 2;
  int p = slot & 3;
  int g = p ^ ((row >> 1) & 3);
  int k = c * 32 + g * 8 + e;
  int mat = row >> 6;
  int h = row & 63;
  const float* W = (mat == 0) ? Wq : ((mat == 1) ? Wk : Wv);
  wt[i] = f2bf(W[k * HDIM + h]);
}

__global__ __launch_bounds__(1024) void head_fused_kernel(
    const float* __restrict__ x, const unsigned short* __restrict__ wt,
    float* __restrict__ out) {
  const int bid = blockIdx.x;        // handles batches 4*bid .. 4*bid+3
  const int tid = threadIdx.x;
  const int w = tid >> 6;            // wave 0..15
  const int ww = w & 3;              // row group: rows [16ww, 16ww+16)
  const int bat = w >> 2;            // 0..3 -> batch 4*bid+bat
  const int lane = tid & 63;
  const int lane15 = lane & 15;
  const int lhi = lane >> 4;

  // LDS 120 KB: [xb0 32K @0][xb1 @32K][xb2 @64K][wb0 12K @96K][wb1 12K @108K].
  // Parking (after streaming): batch r at r*24576: [k 8K][vT 8K][qp 8K].
  __shared__ __align__(16) unsigned char smem[122880];

  // ---- staging addresses ----------------------------------------------------
  // x chunk image per buffer (32 KB): [batch r 8K][row 0..63][phys gran 0..7]
  // x16B; phys granule p holds logical granule p^(row&7); source pre-swizzled.
  // Thread stages slots tid and 1024+tid: batch = slot>>9, rem = slot&511.
  const char* xsrc0;  // slot tid      -> batch tid>>9     (0/1)
  const char* xsrc1;  // slot 1024+tid -> batch 2+(tid>>9) (2/3)
  {
    int rem = tid & 511;
    int row = rem >> 3;
    int p = rem & 7;
    size_t boff = row * (CDIM * 4) + ((p ^ (row & 7)) * 16);
    xsrc0 = (const char*)x +
            (size_t)(PB * bid + (tid >> 9)) * (SEQ * CDIM * 4) + boff;
    xsrc1 = (const char*)x +
            (size_t)(PB * bid + 2 + (tid >> 9)) * (SEQ * CDIM * 4) + boff;
  }
  const int xdst0 = tid * 16;
  const int xdst1 = 16384 + tid * 16;

  // wt: unpadded 12288-B chunks = 12 regions x 1 KB (64 lanes x 16B).
  // Wave w < 12 stages region w. Dest = wave-uniform base + lane*16.
  const char* wsrcA = (const char*)wt + (w * 64 + lane) * 16;
  const int wdstA = (w * 64 + lane) * 16;

  #define STAGE_X(cn, B)                                                    \
    do {                                                                    \
      char* xbp = (char*)smem + (B) * 32768;                                \
      gl_lds16(xsrc0 + (cn) * 128, xbp + xdst0);                            \
      gl_lds16(xsrc1 + (cn) * 128, xbp + xdst1);                            \
    } while (0)
  #define STAGE_W(cn, B)                                                    \
    do {                                                                    \
      char* wbp = (char*)smem + 98304 + (B) * 12288;                        \
      if (w < 12) gl_lds16(wsrcA + (cn) * 12288, wbp + wdstA);              \
    } while (0)

  const f32x4v z4 = {0.f, 0.f, 0.f, 0.f};
  f32x4v accq[4], acck[4], accv[4];
  #pragma unroll
  for (int n = 0; n < 4; ++n) { accq[n] = z4; acck[n] = z4; accv[n] = z4; }

  const int arow = 16 * ww + lane15;
  const int ag0 = (lhi * 2) ^ (arow & 7);
  const int ag1 = (lhi * 2 + 1) ^ (arow & 7);
  const int batoff = bat * 8192;

  // prologue (issue order defines the per-wave vm queue): W0,X0,W1,X1,X2
  STAGE_W(0, 0);
  STAGE_X(0, 0);
  STAGE_W(1, 1);
  STAGE_X(1, 1);
  STAGE_X(2, 2);

  #pragma unroll
  for (int c = 0; c < NCHUNK; ++c) {
    // Derived waits (per-wave queue; a = wt loads/chunk = 1 for waves 0-11,
    // 0 for waves 12-15). At entry: W(c)[a] X(c)[2] W(c+1)[a] X(c+1)[2]
    // X(c+2)[2]. Wait through X(c): leave a+4 (steady), a+2 (c=22), 0 (c=23).
    if (c <= NCHUNK - 3) {
      if (w < 12) asm volatile("s_waitcnt vmcnt(5)" ::: "memory");
      else        asm volatile("s_waitcnt vmcnt(4)" ::: "memory");
    } else if (c == NCHUNK - 2) {
      if (w < 12) asm volatile("s_waitcnt vmcnt(3)" ::: "memory");
      else        asm volatile("s_waitcnt vmcnt(2)" ::: "memory");
    } else {
      asm volatile("s_waitcnt vmcnt(0)" ::: "memory");
    }
    __builtin_amdgcn_s_barrier();

    {  // compute chunk c
      const float* xs = (const float*)((char*)smem + (c % 3) * 32768 + batoff);
      const unsigned short* ws =
          (const unsigned short*)((char*)smem + 98304 + (c & 1) * 12288);
      f32x4v xa = *reinterpret_cast<const f32x4v*>(xs + arow * 32 + ag0 * 4);
      f32x4v xb4 = *reinterpret_cast<const f32x4v*>(xs + arow * 32 + ag1 * 4);
      u16x8 ar;
      #pragma unroll
      for (int i = 0; i < 4; ++i) { ar[i] = f2bf(xa[i]); ar[4 + i] = f2bf(xb4[i]); }
      bf16x8 a = __builtin_bit_cast(bf16x8, ar);
      #pragma unroll
      for (int n = 0; n < 4; ++n) {
        int brq = 0 * HDIM + 16 * n + lane15;
        int bpq = lhi ^ ((brq >> 1) & 3);
        bf16x8 bq = __builtin_bit_cast(bf16x8,
            *reinterpret_cast<const u16x8*>(ws + brq * 32 + bpq * 8));
        accq[n] = mfma16(a, bq, accq[n]);
        int brk = 1 * HDIM + 16 * n + lane15;
        int bpk = lhi ^ ((brk >> 1) & 3);
        bf16x8 bk = __builtin_bit_cast(bf16x8,
            *reinterpret_cast<const u16x8*>(ws + brk * 32 + bpk * 8));
        acck[n] = mfma16(a, bk, acck[n]);
        int brv = 2 * HDIM + 16 * n + lane15;
        int bpv = lhi ^ ((brv >> 1) & 3);
        bf16x8 bv = __builtin_bit_cast(bf16x8,
            *reinterpret_cast<const u16x8*>(ws + brv * 32 + bpv * 8));
        accv[n] = mfma16(a, bv, accv[n]);
      }
    }

    asm volatile("s_waitcnt lgkmcnt(0)" ::: "memory");
    __builtin_amdgcn_s_barrier();

    // refill the buffers just freed (W before X: keeps queue order invariant)
    if (c + 2 < NCHUNK) STAGE_W(c + 2, c & 1);
    if (c + 3 < NCHUNK) STAGE_X(c + 3, c % 3);
  }

  #undef STAGE_X
  #undef STAGE_W

  // ---- parking: k, vT, q as bf16 in swizzled LDS (aliases x buffers) --------
  // C/D layout: col = lane&15, row = (lane>>4)*4 + j   [measured m89/m91]
  unsigned short* k_lds  = (unsigned short*)((char*)smem + bat * 24576);
  unsigned short* vT_lds = (unsigned short*)((char*)smem + bat * 24576 + 8192);
  unsigned short* qp_lds = (unsigned short*)((char*)smem + bat * 24576 + 16384);
  #pragma unroll
  for (int n = 0; n < 4; ++n) {
    int h = 16 * n + lane15;
    #pragma unroll
    for (int j = 0; j < 4; ++j) {
      int s = 16 * ww + lhi * 4 + j;
      k_lds[swz(s, h)] = f2bf(acck[n][j]);
      vT_lds[swz(h, s)] = f2bf(accv[n][j]);
      qp_lds[swz(s, h)] = f2bf(accq[n][j]);
    }
  }
  __syncthreads();

  // ---------------- phase 2: S = q k^T (K over h) -----------------------------
  const int trow = 16 * ww + lane15;
  bf16x8 aq0 = lds_frag(qp_lds, trow, lhi * 8);
  bf16x8 aq1 = lds_frag(qp_lds, trow, 32 + lhi * 8);
  f32x4v accS[4];
  #pragma unroll
  for (int n = 0; n < 4; ++n) accS[n] = z4;
  #pragma unroll
  for (int sB = 0; sB < 4; ++sB) {
    if (sB <= ww) {  // causal: col blocks above the diagonal are all-masked
      bf16x8 bk0 = lds_frag(k_lds, 16 * sB + lane15, lhi * 8);
      bf16x8 bk1 = lds_frag(k_lds, 16 * sB + lane15, 32 + lhi * 8);
      accS[sB] = mfma16(aq0, bk0, accS[sB]);
      accS[sB] = mfma16(aq1, bk1, accS[sB]);
    }
  }

  // ---------------- phase 3: fp32 causal softmax, P -> bf16 LDS ---------------
  float rinv[4];
  #pragma unroll
  for (int j = 0; j < 4; ++j) {
    int t = 16 * ww + lhi * 4 + j;
    float zv[4];
    float m = -3.0e38f;
    #pragma unroll
    for (int sB = 0; sB < 4; ++sB) {
      int s = 16 * sB + lane15;
      float zz = (sB <= ww && s <= t) ? accS[sB][j] * 0.125f : -3.0e38f;
      zv[sB] = zz;
      m = fmaxf(m, zz);
    }
    #pragma unroll
    for (int off = 1; off < 16; off <<= 1) m = fmaxf(m, __shfl_xor(m, off));
    float sum = 0.f;
    float pv[4];
    #pragma unroll
    for (int sB = 0; sB < 4; ++sB) {
      float pe = __expf(zv[sB] - m);  // masked -> exp(-huge) = 0
      pv[sB] = pe;
      sum += pe;
    }
    #pragma unroll
    for (int off = 1; off < 16; off <<= 1) sum += __shfl_xor(sum, off);
    rinv[j] = 1.0f / sum;
    #pragma unroll
    for (int sB = 0; sB < 4; ++sB)
      qp_lds[swz(t, 16 * sB + lane15)] = f2bf(pv[sB]);
  }
  __syncthreads();  // P visible before A-frag reads

  // ---------------- phase 4: O = P V (K over s) -------------------------------
  f32x4v accO[4];
  #pragma unroll
  for (int n = 0; n < 4; ++n) accO[n] = z4;
  #pragma unroll
  for (int s0 = 0; s0 < 64; s0 += 32) {
    if (s0 <= 16 * ww + 15) {  // causal: later s-blocks all zero for this wave
      bf16x8 ap = lds_frag(qp_lds, trow, s0 + lhi * 8);
      #pragma unroll
      for (int n = 0; n < 4; ++n) {
        bf16x8 bv = lds_frag(vT_lds, 16 * n + lane15, s0 + lhi * 8);
        accO[n] = mfma16(ap, bv, accO[n]);
      }
    }
  }

  // ---------------- phase 5: normalize + store fp32 ---------------------------
  float* op = out + (size_t)(PB * bid + bat) * (SEQ * HDIM);
  #pragma unroll
  for (int n = 0; n < 4; ++n) {
    int h = 16 * n + lane15;
    #pragma unroll
    for (int j = 0; j < 4; ++j) {
      int t = 16 * ww + lhi * 4 + j;
      op[t * HDIM + h] = accO[n][j] * rinv[j];
    }
  }
}

extern "C" void kernel_launch(void* const* d_in, const int* in_sizes, int n_in,
                              void* d_out, int out_size, void* d_ws, size_t ws_size,
                              hipStream_t stream) {
  const float* x  = (const float*)d_in[0];
  const float* Wk = (const float*)d_in[1];
  const float* Wq = (const float*)d_in[2];
  const float* Wv = (const float*)d_in[3];
  float* out = (float*)d_out;
  unsigned short* wt = (unsigned short*)d_ws;  // 24 chunks x 12 KB = 288 KiB

  hipLaunchKernelGGL(prep_wt_kernel, dim3((3 * HDIM * CDIM + 255) / 256), dim3(256),
                     0, stream, Wk, Wq, Wv, wt);
  hipLaunchKernelGGL(head_fused_kernel, dim3(BATCHES / PB), dim3(1024), 0, stream,
                     x, wt, out);
}

// Round 16
// 102.665 us; speedup vs baseline: 1.0305x; 1.0305x over previous
//
#include <hip/hip_runtime.h>

// Single-head causal attention — FINAL (best measured, Round 14: 103.3 µs =
// 731 MB VMEM / 7.08 TB/s ≈ 100% of demonstrated fabric ceiling).
// 2-batch 512-thread blocks (2 blocks/CU, two 8-wave barrier domains),
// 3-deep x pipeline + 2-deep unpadded-wt pipeline, derived per-wave counted
// vmcnt, verified swizzled staging and MFMA layouts.
// B=2048, T=64, C=768, H=64. Inputs fp32: x, Wk, Wq, Wv ([in,out] layout).

#define BATCHES 2048
#define SEQ 64
#define CDIM 768
#define HDIM 64
#define NCHUNK 24  // 768 / 32

typedef __bf16 bf16x8 __attribute__((ext_vector_type(8)));
typedef float f32x4v __attribute__((ext_vector_type(4)));
typedef unsigned short u16x8 __attribute__((ext_vector_type(8)));

__device__ __forceinline__ unsigned short f2bf(float f) {
  return __builtin_bit_cast(unsigned short, (__bf16)f);
}

// XOR swizzle for 64-elem bf16 parking rows: elem col ^= ((row&7)<<3)
__device__ __forceinline__ int swz(int row, int col) {
  return row * 64 + (col ^ ((row & 7) << 3));
}

__device__ __forceinline__ f32x4v mfma16(bf16x8 a, bf16x8 b, f32x4v c) {
  return __builtin_amdgcn_mfma_f32_16x16x32_bf16(a, b, c, 0, 0, 0);
}

__device__ __forceinline__ bf16x8 lds_frag(const unsigned short* p, int row, int col) {
  return __builtin_bit_cast(bf16x8, *reinterpret_cast<const u16x8*>(p + swz(row, col)));
}

__device__ __forceinline__ void gl_lds16(const void* g, void* l) {
  __builtin_amdgcn_global_load_lds(
      (const __attribute__((address_space(1))) void*)g,
      (__attribute__((address_space(3))) void*)l, 16, 0, 0);
}

// Prep (verified R4/R7/R10/R14): chunk-major, chunk stride 12288 B (unpadded).
// ws element i: c = i/6144, slot = (i%6144)>>3, e = i&7;
// row = slot>>2 (mat*64+h), p = slot&3, g = p^((row>>1)&3), k = c*32+g*8+e.
__global__ __launch_bounds__(256) void prep_wt_kernel(
    const float* __restrict__ Wk, const float* __restrict__ Wq,
    const float* __restrict__ Wv, unsigned short* __restrict__ wt) {
  int i = blockIdx.x * 256 + threadIdx.x;
  if (i >= 3 * HDIM * CDIM) return;
  int c = i / 6144;
  int r2 = i - c * 6144;
  int slot = r2 >> 3;
  int e = r2 & 7;
  int row = slot >> 2;
  int p = slot & 3;
  int g = p ^ ((row >> 1) & 3);
  int k = c * 32 + g * 8 + e;
  int mat = row >> 6;
  int h = row & 63;
  const float* W = (mat == 0) ? Wq : ((mat == 1) ? Wk : Wv);
  wt[i] = f2bf(W[k * HDIM + h]);
}

__global__ __launch_bounds__(512) void head_fused_kernel(
    const float* __restrict__ x, const unsigned short* __restrict__ wt,
    float* __restrict__ out) {
  const int bid = blockIdx.x;        // handles batches 2*bid, 2*bid+1
  const int tid = threadIdx.x;
  const int w = tid >> 6;            // wave 0..7
  const int ww = w & 3;              // wave-in-batch: rows [16ww, 16ww+16)
  const int bat = w >> 2;            // 0/1
  const int lane = tid & 63;
  const int lane15 = lane & 15;
  const int lhi = lane >> 4;

  // LDS 72 KB: [xb0 16K @0][xb1 @16K][xb2 @32K][wb0 12K @48K][wb1 12K @60K].
  // Parking (after streaming): batch r at r*24576: [k 8K][vT 8K][qp 8K].
  __shared__ __align__(16) unsigned char smem[73728];

  // ---- staging addresses ----------------------------------------------------
  // x chunk image per buffer: [batch r 8K][row 0..63][phys granule 0..7]x16B,
  // phys granule p holds logical granule p^(row&7); source pre-swizzled.
  const char* xsrc0;  // r = 0 -> batch 2*bid
  const char* xsrc1;  // r = 1 -> batch 2*bid+1
  {
    int s = w * 64 + lane;          // 0..511
    int row = s >> 3;
    int p = s & 7;
    size_t boff = row * (CDIM * 4) + ((p ^ (row & 7)) * 16);
    xsrc0 = (const char*)x + (size_t)(2 * bid + 0) * (SEQ * CDIM * 4) + boff;
    xsrc1 = (const char*)x + (size_t)(2 * bid + 1) * (SEQ * CDIM * 4) + boff;
  }
  const int xdst = (w * 64 + lane) * 16;  // within batch-r half: r*8192 + xdst

  // wt: unpadded 12288-B chunks = 12 regions x 1 KB (64 lanes x 16B).
  // Wave w stages region w; waves 0..3 additionally stage region 8+w.
  // Dest = wave-uniform base + lane*16 (contract-safe).
  const char* wsrcA = (const char*)wt + (w * 64 + lane) * 16;
  const char* wsrcB = (const char*)wt + ((8 + w) * 64 + lane) * 16;
  const int wdstA = (w * 64 + lane) * 16;
  const int wdstB = ((8 + w) * 64 + lane) * 16;

  #define STAGE_X(cn, B)                                                    \
    do {                                                                    \
      char* xbp = (char*)smem + (B) * 16384;                                \
      gl_lds16(xsrc0 + (cn) * 128, xbp + 0 * 8192 + xdst);                  \
      gl_lds16(xsrc1 + (cn) * 128, xbp + 1 * 8192 + xdst);                  \
    } while (0)
  #define STAGE_W(cn, B)                                                    \
    do {                                                                    \
      char* wbp = (char*)smem + 49152 + (B) * 12288;                        \
      gl_lds16(wsrcA + (cn) * 12288, wbp + wdstA);                          \
      if (w < 4) gl_lds16(wsrcB + (cn) * 12288, wbp + wdstB);               \
    } while (0)

  const f32x4v z4 = {0.f, 0.f, 0.f, 0.f};
  f32x4v accq[4], acck[4], accv[4];
  #pragma unroll
  for (int n = 0; n < 4; ++n) { accq[n] = z4; acck[n] = z4; accv[n] = z4; }

  const int arow = 16 * ww + lane15;
  const int ag0 = (lhi * 2) ^ (arow & 7);
  const int ag1 = (lhi * 2 + 1) ^ (arow & 7);
  const int batoff = bat * 8192;

  // prologue (issue order defines the per-wave vm queue): W0,X0,W1,X1,X2
  STAGE_W(0, 0);
  STAGE_X(0, 0);
  STAGE_W(1, 1);
  STAGE_X(1, 1);
  STAGE_X(2, 2);

  #pragma unroll
  for (int c = 0; c < NCHUNK; ++c) {
    // Derived waits (per-wave queue; a = wt loads/chunk = 2 for waves 0-3,
    // 1 for waves 4-7). At entry: W(c)[a] X(c)[2] W(c+1)[a] X(c+1)[2] X(c+2)[2].
    // Wait through X(c): leave a+4 (steady), a+2 (c=22), 0 (c=23).
    if (c <= NCHUNK - 3) {
      if (w < 4) asm volatile("s_waitcnt vmcnt(6)" ::: "memory");
      else       asm volatile("s_waitcnt vmcnt(5)" ::: "memory");
    } else if (c == NCHUNK - 2) {
      if (w < 4) asm volatile("s_waitcnt vmcnt(4)" ::: "memory");
      else       asm volatile("s_waitcnt vmcnt(3)" ::: "memory");
    } else {
      asm volatile("s_waitcnt vmcnt(0)" ::: "memory");
    }
    __builtin_amdgcn_s_barrier();

    {  // compute chunk c
      const float* xs = (const float*)((char*)smem + (c % 3) * 16384 + batoff);
      const unsigned short* ws =
          (const unsigned short*)((char*)smem + 49152 + (c & 1) * 12288);
      f32x4v xa = *reinterpret_cast<const f32x4v*>(xs + arow * 32 + ag0 * 4);
      f32x4v xb4 = *reinterpret_cast<const f32x4v*>(xs + arow * 32 + ag1 * 4);
      u16x8 ar;
      #pragma unroll
      for (int i = 0; i < 4; ++i) { ar[i] = f2bf(xa[i]); ar[4 + i] = f2bf(xb4[i]); }
      bf16x8 a = __builtin_bit_cast(bf16x8, ar);
      #pragma unroll
      for (int n = 0; n < 4; ++n) {
        int brq = 0 * HDIM + 16 * n + lane15;
        int bpq = lhi ^ ((brq >> 1) & 3);
        bf16x8 bq = __builtin_bit_cast(bf16x8,
            *reinterpret_cast<const u16x8*>(ws + brq * 32 + bpq * 8));
        accq[n] = mfma16(a, bq, accq[n]);
        int brk = 1 * HDIM + 16 * n + lane15;
        int bpk = lhi ^ ((brk >> 1) & 3);
        bf16x8 bk = __builtin_bit_cast(bf16x8,
            *reinterpret_cast<const u16x8*>(ws + brk * 32 + bpk * 8));
        acck[n] = mfma16(a, bk, acck[n]);
        int brv = 2 * HDIM + 16 * n + lane15;
        int bpv = lhi ^ ((brv >> 1) & 3);
        bf16x8 bv = __builtin_bit_cast(bf16x8,
            *reinterpret_cast<const u16x8*>(ws + brv * 32 + bpv * 8));
        accv[n] = mfma16(a, bv, accv[n]);
      }
    }

    asm volatile("s_waitcnt lgkmcnt(0)" ::: "memory");
    __builtin_amdgcn_s_barrier();

    // refill the buffers just freed (W before X: keeps queue order invariant)
    if (c + 2 < NCHUNK) STAGE_W(c + 2, c & 1);
    if (c + 3 < NCHUNK) STAGE_X(c + 3, c % 3);
  }

  #undef STAGE_X
  #undef STAGE_W

  // ---- parking: k, vT, q as bf16 in swizzled LDS (aliases x buffers) --------
  // C/D layout: col = lane&15, row = (lane>>4)*4 + j   [measured m89/m91]
  unsigned short* k_lds  = (unsigned short*)((char*)smem + bat * 24576);
  unsigned short* vT_lds = (unsigned short*)((char*)smem + bat * 24576 + 8192);
  unsigned short* qp_lds = (unsigned short*)((char*)smem + bat * 24576 + 16384);
  #pragma unroll
  for (int n = 0; n < 4; ++n) {
    int h = 16 * n + lane15;
    #pragma unroll
    for (int j = 0; j < 4; ++j) {
      int s = 16 * ww + lhi * 4 + j;
      k_lds[swz(s, h)] = f2bf(acck[n][j]);
      vT_lds[swz(h, s)] = f2bf(accv[n][j]);
      qp_lds[swz(s, h)] = f2bf(accq[n][j]);
    }
  }
  __syncthreads();

  // ---------------- phase 2: S = q k^T (K over h) -----------------------------
  const int trow = 16 * ww + lane15;
  bf16x8 aq0 = lds_frag(qp_lds, trow, lhi * 8);
  bf16x8 aq1 = lds_frag(qp_lds, trow, 32 + lhi * 8);
  f32x4v accS[4];
  #pragma unroll
  for (int n = 0; n < 4; ++n) accS[n] = z4;
  #pragma unroll
  for (int sB = 0; sB < 4; ++sB) {
    if (sB <= ww) {  // causal: col blocks above the diagonal are all-masked
      bf16x8 bk0 = lds_frag(k_lds, 16 * sB + lane15, lhi * 8);
      bf16x8 bk1 = lds_frag(k_lds, 16 * sB + lane15, 32 + lhi * 8);
      accS[sB] = mfma16(aq0, bk0, accS[sB]);
      accS[sB] = mfma16(aq1, bk1, accS[sB]);
    }
  }

  // ---------------- phase 3: fp32 causal softmax, P -> bf16 LDS ---------------
  float rinv[4];
  #pragma unroll
  for (int j = 0; j < 4; ++j) {
    int t = 16 * ww + lhi * 4 + j;
    float zv[4];
    float m = -3.0e38f;
    #pragma unroll
    for (int sB = 0; sB < 4; ++sB) {
      int s = 16 * sB + lane15;
      float zz = (sB <= ww && s <= t) ? accS[sB][j] * 0.125f : -3.0e38f;
      zv[sB] = zz;
      m = fmaxf(m, zz);
    }
    #pragma unroll
    for (int off = 1; off < 16; off <<= 1) m = fmaxf(m, __shfl_xor(m, off));
    float sum = 0.f;
    float pv[4];
    #pragma unroll
    for (int sB = 0; sB < 4; ++sB) {
      float pe = __expf(zv[sB] - m);  // masked -> exp(-huge) = 0
      pv[sB] = pe;
      sum += pe;
    }
    #pragma unroll
    for (int off = 1; off < 16; off <<= 1) sum += __shfl_xor(sum, off);
    rinv[j] = 1.0f / sum;
    #pragma unroll
    for (int sB = 0; sB < 4; ++sB)
      qp_lds[swz(t, 16 * sB + lane15)] = f2bf(pv[sB]);
  }
  __syncthreads();  // P visible before A-frag reads

  // ---------------- phase 4: O = P V (K over s) -------------------------------
  f32x4v accO[4];
  #pragma unroll
  for (int n = 0; n < 4; ++n) accO[n] = z4;
  #pragma unroll
  for (int s0 = 0; s0 < 64; s0 += 32) {
    if (s0 <= 16 * ww + 15) {  // causal: later s-blocks all zero for this wave
      bf16x8 ap = lds_frag(qp_lds, trow, s0 + lhi * 8);
      #pragma unroll
      for (int n = 0; n < 4; ++n) {
        bf16x8 bv = lds_frag(vT_lds, 16 * n + lane15, s0 + lhi * 8);
        accO[n] = mfma16(ap, bv, accO[n]);
      }
    }
  }

  // ---------------- phase 5: normalize + store fp32 ---------------------------
  float* op = out + (size_t)(2 * bid + bat) * (SEQ * HDIM);
  #pragma unroll
  for (int n = 0; n < 4; ++n) {
    int h = 16 * n + lane15;
    #pragma unroll
    for (int j = 0; j < 4; ++j) {
      int t = 16 * ww + lhi * 4 + j;
      op[t * HDIM + h] = accO[n][j] * rinv[j];
    }
  }
}

extern "C" void kernel_launch(void* const* d_in, const int* in_sizes, int n_in,
                              void* d_out, int out_size, void* d_ws, size_t ws_size,
                              hipStream_t stream) {
  const float* x  = (const float*)d_in[0];
  const float* Wk = (const float*)d_in[1];
  const float* Wq = (const float*)d_in[2];
  const float* Wv = (const float*)d_in[3];
  float* out = (float*)d_out;
  unsigned short* wt = (unsigned short*)d_ws;  // 24 chunks x 12 KB = 288 KiB

  hipLaunchKernelGGL(prep_wt_kernel, dim3((3 * HDIM * CDIM + 255) / 256), dim3(256),
                     0, stream, Wk, Wq, Wv, wt);
  hipLaunchKernelGGL(head_fused_kernel, dim3(BATCHES / 2), dim3(512), 0, stream,
                     x, wt, out);
}